// Round 1
// baseline (443.549 us; speedup 1.0000x reference)
//
#include <hip/hip_runtime.h>
#include <hip/hip_bf16.h>

// Problem: b=64, o=16, c=128, s=400, fp32 I/O.
// Mathematical simplification: sum(softmax(atten),-1) == 1, so the whole
// q/k/attention branch is the identity. Remaining work:
//   out[bo,c,s] = LN_c( Wp @ x[bo,:,s] + bp ; gp, betap ) + x[bo,c,s]
// Implemented as a batched MFMA GEMM (Z = Wp(128x128) @ X(128x400) per bo)
// fused with a per-column LayerNorm and the residual add.

#define BO 1024
#define CC 128
#define SS 400
#define TS 80          // s-columns per block
#define NW 5           // waves per block
#define NT (NW * 64)
#define XSTRIDE 82     // LDS row stride (fp32 elems); breaks 4-way bank conflicts

typedef __attribute__((ext_vector_type(8))) short short8;
typedef __attribute__((ext_vector_type(4))) float f32x4;

// Pre-convert Wp (fp32 row-major 128x128) to bf16 in workspace so the main
// kernel's A-fragment loads are 16B bf16 vectors (L1/L2-hot, 32 KiB total).
__global__ void wp_cvt_kernel(const float* __restrict__ wp,
                              __hip_bfloat16* __restrict__ out) {
    int i = blockIdx.x * 256 + threadIdx.x;   // 64 blocks x 256 = 16384
    out[i] = __float2bfloat16(wp[i]);
}

__global__ __launch_bounds__(NT) void ca_main_kernel(
    const float* __restrict__ x,
    const __hip_bfloat16* __restrict__ wpb,   // bf16 Wp [128][128]
    const float* __restrict__ bp,
    const float* __restrict__ gp,
    const float* __restrict__ betap,
    float* __restrict__ out)
{
    __shared__ float xs[CC * XSTRIDE];        // 128 x 82 fp32 = 41 KiB

    const int bo = blockIdx.y;
    const int s0 = blockIdx.x * TS;
    const int t  = threadIdx.x;
    const size_t base = (size_t)bo * (CC * SS);

    // ---- stage x tile [128][80] fp32 -> LDS (row stride 82) ----
    {
        const int r   = t / 20;               // 0..15
        const int col = (t % 20) * 4;         // 0,4,...,76
        #pragma unroll
        for (int it = 0; it < 8; ++it) {
            const int c = it * 16 + r;        // 0..127
            const float4 v = *reinterpret_cast<const float4*>(
                x + base + (size_t)c * SS + s0 + col);
            const int di = c * XSTRIDE + col; // even -> 8B aligned
            *reinterpret_cast<float2*>(&xs[di])     = make_float2(v.x, v.y);
            *reinterpret_cast<float2*>(&xs[di + 2]) = make_float2(v.z, v.w);
        }
    }
    __syncthreads();

    const int lane = t & 63;
    const int wid  = t >> 6;
    const int lcol = lane & 15;               // n-index within 16x16 tile
    const int lgrp = lane >> 4;               // 0..3
    const int scol = wid * 16 + lcol;         // s-column within block tile

    // ---- B fragments: B[k][n] with k = kk*32 + lgrp*8 + i, n = lcol ----
    short8 bfrag[4];
    #pragma unroll
    for (int kk = 0; kk < 4; ++kk) {
        #pragma unroll
        for (int i = 0; i < 8; ++i) {
            const int k = kk * 32 + lgrp * 8 + i;
            const float f = xs[k * XSTRIDE + scol];
            const __hip_bfloat16 h = __float2bfloat16(f);
            bfrag[kk][i] = (short)__builtin_bit_cast(unsigned short, h);
        }
    }

    // ---- K-loop: acc[m] += A(Wp tile m,kk) * B(kk) ----
    f32x4 acc[8];
    #pragma unroll
    for (int m = 0; m < 8; ++m) acc[m] = (f32x4){0.f, 0.f, 0.f, 0.f};

    const short8* wpa = reinterpret_cast<const short8*>(wpb);
    #pragma unroll
    for (int kk = 0; kk < 4; ++kk) {
        #pragma unroll
        for (int m = 0; m < 8; ++m) {
            // A[mrow][k]: mrow = lcol, k = kk*32 + lgrp*8 + i (contiguous 16B)
            const short8 a = wpa[((m * 16 + lcol) * CC + kk * 32 + lgrp * 8) >> 3];
            acc[m] = __builtin_amdgcn_mfma_f32_16x16x32_bf16(a, bfrag[kk], acc[m], 0, 0, 0);
        }
    }

    // ---- epilogue: per-column LayerNorm over c (128), + residual ----
    // C/D layout: row(c within tile) = lgrp*4 + j, col(s) = lcol.
    float sum = 0.f, sq = 0.f;
    #pragma unroll
    for (int m = 0; m < 8; ++m) {
        #pragma unroll
        for (int j = 0; j < 4; ++j) {
            const int c = m * 16 + lgrp * 4 + j;
            const float z = acc[m][j] + bp[c];
            acc[m][j] = z;
            sum += z;
            sq  += z * z;
        }
    }
    // column owned by lanes {lcol, lcol+16, lcol+32, lcol+48}
    sum += __shfl_xor(sum, 16);
    sum += __shfl_xor(sum, 32);
    sq  += __shfl_xor(sq, 16);
    sq  += __shfl_xor(sq, 32);

    const float mean = sum * (1.f / 128.f);
    const float var  = sq * (1.f / 128.f) - mean * mean;
    const float rinv = rsqrtf(var + 1e-5f);

    float* op = out + base + s0 + scol;
    #pragma unroll
    for (int m = 0; m < 8; ++m) {
        #pragma unroll
        for (int j = 0; j < 4; ++j) {
            const int c = m * 16 + lgrp * 4 + j;
            const float y = (acc[m][j] - mean) * rinv * gp[c] + betap[c]
                          + xs[c * XSTRIDE + scol];
            op[(size_t)c * SS] = y;
        }
    }
}

extern "C" void kernel_launch(void* const* d_in, const int* in_sizes, int n_in,
                              void* d_out, int out_size, void* d_ws, size_t ws_size,
                              hipStream_t stream) {
    // setup_inputs order: 0:x 1:Wq 2:bq 3:gq 4:betaq 5:Wk 6:bk 7:gk 8:betak
    //                     9:Wp 10:bp 11:gp 12:betap   (all fp32)
    const float* x     = (const float*)d_in[0];
    const float* Wp    = (const float*)d_in[9];
    const float* bp    = (const float*)d_in[10];
    const float* gp    = (const float*)d_in[11];
    const float* betap = (const float*)d_in[12];
    __hip_bfloat16* wpb = (__hip_bfloat16*)d_ws;   // 32 KiB scratch

    wp_cvt_kernel<<<dim3(64), dim3(256), 0, stream>>>(Wp, wpb);
    ca_main_kernel<<<dim3(SS / TS, BO), dim3(NT), 0, stream>>>(
        x, wpb, bp, gp, betap, (float*)d_out);
}

// Round 2
// 414.607 us; speedup vs baseline: 1.0698x; 1.0698x over previous
//
#include <hip/hip_runtime.h>
#include <hip/hip_bf16.h>

// out[bo,c,s] = LN_c( Wp @ x[bo,:,s] + bp ; gp, betap ) + x[bo,c,s]
// (softmax row-sums are identically 1 => attention branch is the identity)
//
// Round-2 structure: Wp (bf16, 32 KiB) lives in LDS, pre-swizzled by the
// converter kernel so global_load_lds stays linear and ds_read_b128 is
// conflict-free (XOR swizzle byte ^= ((row&7)<<4)). x is read directly from
// global: each B-fragment load instruction covers 4x64B aligned segments,
// and the epilogue residual re-reads the same segments (L1-hot). Waves are
// independent after one barrier -> latency-bound no more.

#define CC 128
#define SS 400
#define NT 320

typedef __attribute__((ext_vector_type(8))) short short8;
typedef __attribute__((ext_vector_type(4))) float f32x4;

// Convert Wp fp32 -> bf16 into workspace, PRE-SWIZZLED so that after a linear
// global->LDS copy, LDS byte L holds logical byte L ^ ((row(L)&7)<<4).
__global__ void wp_cvt_kernel(const float* __restrict__ wp,
                              unsigned short* __restrict__ wpb) {
    const int e = blockIdx.x * 256 + threadIdx.x;   // 0..16383
    const int L = e << 1;                            // byte index
    const int B = L ^ (((L >> 8) & 7) << 4);         // involution, row-preserving
    const __hip_bfloat16 h = __float2bfloat16(wp[B >> 1]);
    wpb[e] = __builtin_bit_cast(unsigned short, h);
}

__global__ __launch_bounds__(NT, 5) void ca_main_kernel(
    const float* __restrict__ x,
    const unsigned short* __restrict__ wpb,   // pre-swizzled bf16 Wp
    const float* __restrict__ bp,
    const float* __restrict__ gp,
    const float* __restrict__ betap,
    float* __restrict__ out)
{
    __shared__ unsigned short As[CC * CC];    // exactly 32 KiB -> 5 blocks/CU

    const int bo   = blockIdx.y;
    const int s0   = blockIdx.x * 80;
    const int t    = threadIdx.x;
    const int lane = t & 63;
    const int wid  = t >> 6;
    const int lcol = lane & 15;               // n-index / A-row low bits
    const int lgrp = lane >> 4;               // 0..3
    const int scol = s0 + wid * 16 + lcol;    // this lane's s-column
    const size_t base = (size_t)bo * (CC * SS);
    const float* xb = x + base + scol;

    // ---- issue B loads early (16-lane groups hit aligned 64B segments) ----
    float raw[32];
    #pragma unroll
    for (int kk = 0; kk < 4; ++kk)
        #pragma unroll
        for (int i = 0; i < 8; ++i)
            raw[kk * 8 + i] = xb[(size_t)(kk * 32 + lgrp * 8 + i) * SS];

    // ---- stage pre-swizzled Wp into LDS (async DMA, linear dest) ----
    for (int j = wid; j < 32; j += 5) {
        __builtin_amdgcn_global_load_lds(
            (const __attribute__((address_space(1))) unsigned int*)
                ((const char*)wpb + j * 1024 + lane * 16),
            (__attribute__((address_space(3))) unsigned int*)
                ((char*)As + j * 1024),
            16, 0, 0);
    }

    // ---- pack B fragments to bf16 while staging is in flight ----
    short8 bfrag[4];
    #pragma unroll
    for (int kk = 0; kk < 4; ++kk)
        #pragma unroll
        for (int i = 0; i < 8; ++i) {
            const __hip_bfloat16 h = __float2bfloat16(raw[kk * 8 + i]);
            bfrag[kk][i] = (short)__builtin_bit_cast(unsigned short, h);
        }

    __syncthreads();

    // ---- MFMA: acc[m] += A(Wp rows m*16+lcol, k-slice kk) * B ----
    f32x4 acc[8];
    #pragma unroll
    for (int m = 0; m < 8; ++m) acc[m] = (f32x4){0.f, 0.f, 0.f, 0.f};

    const int axor = (lcol & 7) << 4;         // lane-constant XOR swizzle
    const char* asb = (const char*)As;
    #pragma unroll
    for (int kk = 0; kk < 4; ++kk) {
        #pragma unroll
        for (int m = 0; m < 8; ++m) {
            const short8 a = *reinterpret_cast<const short8*>(
                asb + ((((m * 16 + lcol) * 256) + kk * 64 + lgrp * 16) ^ axor));
            acc[m] = __builtin_amdgcn_mfma_f32_16x16x32_bf16(a, bfrag[kk], acc[m], 0, 0, 0);
        }
    }

    // ---- epilogue: LayerNorm over c (column of 128) + residual ----
    // C/D layout: row(c in tile) = lgrp*4 + j, col(s) = lcol  [validated r0]
    float sum = 0.f, sq = 0.f;
    #pragma unroll
    for (int m = 0; m < 8; ++m)
        #pragma unroll
        for (int j = 0; j < 4; ++j) {
            const int c = m * 16 + lgrp * 4 + j;
            const float z = acc[m][j] + bp[c];
            acc[m][j] = z;
            sum += z;
            sq  += z * z;
        }
    sum += __shfl_xor(sum, 16);
    sum += __shfl_xor(sum, 32);
    sq  += __shfl_xor(sq, 16);
    sq  += __shfl_xor(sq, 32);

    const float mean = sum * (1.f / 128.f);
    const float var  = sq * (1.f / 128.f) - mean * mean;
    const float rinv = rsqrtf(var + 1e-5f);

    float* op = out + base + scol;
    #pragma unroll
    for (int m = 0; m < 8; ++m)
        #pragma unroll
        for (int j = 0; j < 4; ++j) {
            const int c = m * 16 + lgrp * 4 + j;
            const float y = (acc[m][j] - mean) * rinv * gp[c] + betap[c]
                          + xb[(size_t)c * SS];      // residual: L1-hot segment
            op[(size_t)c * SS] = y;
        }
}

extern "C" void kernel_launch(void* const* d_in, const int* in_sizes, int n_in,
                              void* d_out, int out_size, void* d_ws, size_t ws_size,
                              hipStream_t stream) {
    const float* x     = (const float*)d_in[0];
    const float* Wp    = (const float*)d_in[9];
    const float* bp    = (const float*)d_in[10];
    const float* gp    = (const float*)d_in[11];
    const float* betap = (const float*)d_in[12];
    unsigned short* wpb = (unsigned short*)d_ws;   // 32 KiB scratch

    wp_cvt_kernel<<<dim3(64), dim3(256), 0, stream>>>(Wp, wpb);
    ca_main_kernel<<<dim3(SS / 80, 1024), dim3(NT), 0, stream>>>(
        x, wpb, bp, gp, betap, (float*)d_out);
}